// Round 8
// baseline (166.330 us; speedup 1.0000x reference)
//
#include <hip/hip_runtime.h>
#include <math.h>
#include <stdint.h>

// Problem constants (B,S,E) = (8, 4096, 1024), all fp32.
constexpr int Bc  = 8;
constexpr int Sc  = 4096;
constexpr int Ec  = 1024;
constexpr int BEc = Bc * Ec;   // 8192 (b,e) columns
constexpr int NP  = 8;         // second-stage reduction parts
constexpr int NSmain = 256;    // s-chunks for the streaming kernels
constexpr int SCmain = Sc / NSmain;  // 16 rows per chunk

// native 4-wide float vector (works with nontemporal builtins)
typedef float f4 __attribute__((ext_vector_type(4)));

// fast feature map: gelu(x)+1 with A&S 7.1.26 erf (|eps| <= 1.5e-7)
__device__ __forceinline__ float fast_feat(float x) {
    float a = fabsf(x) * 0.70710678118654752f;          // |x|/sqrt(2)
    float t = __builtin_amdgcn_rcpf(fmaf(0.3275911f, a, 1.0f));
    float p = fmaf(1.061405429f, t, -1.453152027f);
    p = fmaf(p, t, 1.421413741f);
    p = fmaf(p, t, -0.284496736f);
    p = fmaf(p, t, 0.254829592f);
    float e  = __expf(-a * a);
    float er = fmaf(-p * t, e, 1.0f);                   // erf(|x|/sqrt2)
    er = copysignf(er, x);
    return fmaf(0.5f * x, 1.0f + er, 1.0f);
}
__device__ __forceinline__ f4 feat4(f4 v) {
    f4 r;
    r.x = fast_feat(v.x); r.y = fast_feat(v.y);
    r.z = fast_feat(v.z); r.w = fast_feat(v.w);
    return r;
}

#define GLOAD_LDS(gsrc, ldst)                                                   \
    __builtin_amdgcn_global_load_lds(                                           \
        (const __attribute__((address_space(1))) uint32_t*)(gsrc),              \
        (__attribute__((address_space(3))) uint32_t*)(ldst), 16, 0, 0)

// ---------------- K1: colsum(qf*kf) and max(qf) per (b,e), s-chunk ----------
// m97-faithful async staging: STAGE(next tile) -> COMPUTE(cur) ->
// __syncthreads() (compiler auto-drains vmcnt(0) before the barrier, AFTER
// compute, so next-tile loads overlap compute). Tile = 2 rows x {Q,K} =
// 16 KB; double-buffered = 32 KB LDS -> 5 blocks/CU.
// Each wave stages and consumes its own 256-float row segments (linear
// dest, lane i's 16 B at base + lane*16 per m104).
__global__ void __launch_bounds__(256)
sa_stats_part(const float* __restrict__ qp, const float* __restrict__ kp,
              float* __restrict__ psum, float* __restrict__ pmax) {
    __shared__ f4 lds[2048];   // [buf2][row2][stream2][wave4][lane64] f4
    const int chunk = blockIdx.x, b = blockIdx.y;
    const int tid = threadIdx.x, wid = tid >> 6, lane = tid & 63;
    const size_t rowbase = ((size_t)b * Sc + (size_t)chunk * 16) * Ec;
    const float* qb = qp + rowbase + wid * 256 + lane * 4;
    const float* kb = kp + rowbase + wid * 256 + lane * 4;

    f4 s  = (f4)(0.f);
    f4 mx = (f4)(-1e30f);

    // f4-index of wave-uniform LDS base for (buf,row,stream)
#define LIDX(buf, r, st) ((((((buf) * 2 + (r)) * 2 + (st)) * 4) + wid) * 64)

#define STAGE(t, buf)                                                           \
    {                                                                           \
        _Pragma("unroll")                                                       \
        for (int r = 0; r < 2; ++r) {                                           \
            GLOAD_LDS(qb + (size_t)((t) * 2 + r) * Ec, &lds[LIDX(buf, r, 0)]);  \
            GLOAD_LDS(kb + (size_t)((t) * 2 + r) * Ec, &lds[LIDX(buf, r, 1)]);  \
        }                                                                       \
    }

    STAGE(0, 0);
    __syncthreads();                 // vmcnt(0) auto-inserted: tile0 landed
#pragma unroll
    for (int t = 0; t < 8; ++t) {
        const int cur = t & 1;
        if (t < 7) STAGE(t + 1, cur ^ 1);   // in flight during compute
#pragma unroll
        for (int r = 0; r < 2; ++r) {
            f4 qv = lds[LIDX(cur, r, 0) + lane];
            f4 kv = lds[LIDX(cur, r, 1) + lane];
            f4 qf = feat4(qv);
            f4 kf = feat4(kv);
            s.x = fmaf(qf.x, kf.x, s.x);  mx.x = fmaxf(mx.x, qf.x);
            s.y = fmaf(qf.y, kf.y, s.y);  mx.y = fmaxf(mx.y, qf.y);
            s.z = fmaf(qf.z, kf.z, s.z);  mx.z = fmaxf(mx.z, qf.z);
            s.w = fmaf(qf.w, kf.w, s.w);  mx.w = fmaxf(mx.w, qf.w);
        }
        __syncthreads();             // drains next tile's loads AFTER compute
    }
#undef STAGE
#undef LIDX

    const int o = chunk * BEc + b * Ec + (wid * 256 + lane * 4);
    *(f4*)(psum + o) = s;
    *(f4*)(pmax + o) = mx;
}

// K2a: reduce NS stats chunks -> NP parts. grid = (NP, BEc/256).
__global__ void __launch_bounds__(256)
sa_red2(const float* __restrict__ psum, const float* __restrict__ pmax,
        float* __restrict__ psumB, float* __restrict__ pmaxB, int SC2) {
    const int id = blockIdx.y * 256 + threadIdx.x;
    const int p  = blockIdx.x;
    float s = 0.f, mx = -1e30f;
    int off = p * SC2 * BEc + id;
    for (int ch = 0; ch < SC2; ++ch, off += BEc) {
        s += psum[off];
        mx = fmaxf(mx, pmax[off]);
    }
    psumB[p * BEc + id] = s;
    pmaxB[p * BEc + id] = mx;
}

// K2b: finalize stats -> c[b,e] = colsum/32 (>0); eMax = c*max
__global__ void __launch_bounds__(256)
sa_stats_fin(const float* __restrict__ psumB, const float* __restrict__ pmaxB,
             float* __restrict__ cbuf, float* __restrict__ embuf) {
    const int id = blockIdx.x * blockDim.x + threadIdx.x;
    float s = 0.f, mx = -1e30f;
#pragma unroll
    for (int p = 0; p < NP; ++p) {
        s += psumB[p * BEc + id];
        mx = fmaxf(mx, pmaxB[p * BEc + id]);
    }
    const float c = s * (1.0f / 32.0f);   // 1/sqrt(1024), c > 0 guaranteed
    cbuf[id]  = c;
    embuf[id] = c * mx;
}

// ---------------- K3: partial denominator sum_s exp(c*qf - eMax) ------------
template<int SC>
__global__ void __launch_bounds__(256)
sa_den_part(const float* __restrict__ qp, const float* __restrict__ cbuf,
            const float* __restrict__ embuf, float* __restrict__ pden) {
    const int chunk = blockIdx.x, b = blockIdx.y;
    const int e = threadIdx.x * 4;
    const f4 c4 = *(const f4*)(cbuf + b * Ec + e);
    const f4 m4 = *(const f4*)(embuf + b * Ec + e);
    const float* qb = qp + (b * Sc + chunk * SC) * Ec + e;

    f4 d = (f4)(0.f);
#pragma unroll 4
    for (int r = 0; r < SC; ++r) {
        f4 qf = feat4(*(const f4*)(qb + r * Ec));
        d.x += __expf(fmaf(c4.x, qf.x, -m4.x));
        d.y += __expf(fmaf(c4.y, qf.y, -m4.y));
        d.z += __expf(fmaf(c4.z, qf.z, -m4.z));
        d.w += __expf(fmaf(c4.w, qf.w, -m4.w));
    }
    const int o = chunk * BEc + b * Ec + e;
    *(f4*)(pden + o) = d;
}

// K4a: reduce NS denom chunks -> NP parts. grid = (NP, BEc/256).
__global__ void __launch_bounds__(256)
sa_red1(const float* __restrict__ pden, float* __restrict__ pdenB, int SC2) {
    const int id = blockIdx.y * 256 + threadIdx.x;
    const int p  = blockIdx.x;
    float s = 0.f;
    int off = p * SC2 * BEc + id;
    for (int ch = 0; ch < SC2; ++ch, off += BEc) s += pden[off];
    pdenB[p * BEc + id] = s;
}

// K4b: finalize denominator -> reciprocal
__global__ void __launch_bounds__(256)
sa_den_fin(const float* __restrict__ pdenB, float* __restrict__ rdbuf) {
    const int id = blockIdx.x * blockDim.x + threadIdx.x;
    float s = 0.f;
#pragma unroll
    for (int p = 0; p < NP; ++p) s += pdenB[p * BEc + id];
    rdbuf[id] = 1.0f / s;
}

// ---------------- K5: out = exp(c*qf - eMax) * rdenom * values --------------
// V load + out store stay nontemporal: protects Q's L3 residency.
template<int SC>
__global__ void __launch_bounds__(256)
sa_out(const float* __restrict__ qp, const float* __restrict__ vp,
       const float* __restrict__ cbuf, const float* __restrict__ embuf,
       const float* __restrict__ rdbuf, float* __restrict__ outp) {
    const int chunk = blockIdx.x, b = blockIdx.y;
    const int e = threadIdx.x * 4;
    const f4 c4 = *(const f4*)(cbuf + b * Ec + e);
    const f4 m4 = *(const f4*)(embuf + b * Ec + e);
    const f4 r4 = *(const f4*)(rdbuf + b * Ec + e);
    const int base0 = (b * Sc + chunk * SC) * Ec + e;
    const float* qb = qp + base0;
    const float* vb = vp + base0;
    float* ob = outp + base0;

#pragma unroll 4
    for (int r = 0; r < SC; ++r) {
        f4 qf = feat4(*(const f4*)(qb + r * Ec));
        f4 vv = __builtin_nontemporal_load((const f4*)(vb + r * Ec));
        f4 o;
        o.x = __expf(fmaf(c4.x, qf.x, -m4.x)) * r4.x * vv.x;
        o.y = __expf(fmaf(c4.y, qf.y, -m4.y)) * r4.y * vv.y;
        o.z = __expf(fmaf(c4.z, qf.z, -m4.z)) * r4.z * vv.z;
        o.w = __expf(fmaf(c4.w, qf.w, -m4.w)) * r4.w * vv.w;
        __builtin_nontemporal_store(o, (f4*)(ob + r * Ec));
    }
}

extern "C" void kernel_launch(void* const* d_in, const int* in_sizes, int n_in,
                              void* d_out, int out_size, void* d_ws, size_t ws_size,
                              hipStream_t stream) {
    const float* q = (const float*)d_in[0];
    const float* k = (const float*)d_in[1];
    const float* v = (const float*)d_in[2];
    float* out = (float*)d_out;

    const int NS = NSmain;     // ws usage ~17 MB
    const int SC2 = NS / NP;

    float* w     = (float*)d_ws;
    float* psum  = w;
    float* pmax  = psum  + (size_t)NS * BEc;
    float* psumB = pmax  + (size_t)NS * BEc;
    float* pmaxB = psumB + (size_t)NP * BEc;
    float* cbuf  = pmaxB + (size_t)NP * BEc;
    float* embuf = cbuf  + BEc;
    float* rdbuf = embuf + BEc;
    float* pden  = psum;    // reused after K2a
    float* pdenB = psumB;   // reused after K2b

    dim3 gridP(NS, Bc);
    dim3 gridR(NP, BEc / 256);
    sa_stats_part<<<gridP, 256, 0, stream>>>(q, k, psum, pmax);
    sa_red2<<<gridR, 256, 0, stream>>>(psum, pmax, psumB, pmaxB, SC2);
    sa_stats_fin<<<BEc / 256, 256, 0, stream>>>(psumB, pmaxB, cbuf, embuf);
    sa_den_part<SCmain><<<gridP, 256, 0, stream>>>(q, cbuf, embuf, pden);
    sa_red1<<<gridR, 256, 0, stream>>>(pden, pdenB, SC2);
    sa_den_fin<<<BEc / 256, 256, 0, stream>>>(pdenB, rdbuf);
    sa_out<SCmain><<<gridP, 256, 0, stream>>>(q, v, cbuf, embuf, rdbuf, out);
}

// Round 9
// 158.293 us; speedup vs baseline: 1.0508x; 1.0508x over previous
//
#include <hip/hip_runtime.h>
#include <math.h>

// Problem constants (B,S,E) = (8, 4096, 1024), all fp32.
constexpr int Bc  = 8;
constexpr int Sc  = 4096;
constexpr int Ec  = 1024;
constexpr int BEc = Bc * Ec;   // 8192 (b,e) columns
constexpr int NP  = 8;         // second-stage reduction parts
constexpr int NSmain = 256;    // s-chunks for the streaming kernels
constexpr int SCmain = Sc / NSmain;  // 16 rows per chunk

// native 4-wide float vector (works with nontemporal builtins)
typedef float f4 __attribute__((ext_vector_type(4)));

// fast feature map: gelu(x)+1 with A&S 7.1.26 erf (|eps| <= 1.5e-7)
__device__ __forceinline__ float fast_feat(float x) {
    float a = fabsf(x) * 0.70710678118654752f;          // |x|/sqrt(2)
    float t = __builtin_amdgcn_rcpf(fmaf(0.3275911f, a, 1.0f));
    float p = fmaf(1.061405429f, t, -1.453152027f);
    p = fmaf(p, t, 1.421413741f);
    p = fmaf(p, t, -0.284496736f);
    p = fmaf(p, t, 0.254829592f);
    float e  = __expf(-a * a);
    float er = fmaf(-p * t, e, 1.0f);                   // erf(|x|/sqrt2)
    er = copysignf(er, x);
    return fmaf(0.5f * x, 1.0f + er, 1.0f);
}
__device__ __forceinline__ f4 feat4(f4 v) {
    f4 r;
    r.x = fast_feat(v.x); r.y = fast_feat(v.y);
    r.z = fast_feat(v.z); r.w = fast_feat(v.w);
    return r;
}

// ---------------- K1: colsum(qf*kf) and max(qf) per (b,e), s-chunk ----------
// qf,kf > 0.83 always => colsum > 0 => c > 0 => eMax = c*max(qf) (min dead).
// K loads are NONTEMPORAL (read-once stream; keeps Q resident in L2/L3 —
// the one ingredient that measurably sped K1 up: R3 82us vs R6 103us).
// Q loads stay cached: K1 installs Q into L3 for K3/K5 re-reads.
template<int SC>
__global__ void __launch_bounds__(256)
sa_stats_part(const float* __restrict__ qp, const float* __restrict__ kp,
              float* __restrict__ psum, float* __restrict__ pmax) {
    const int chunk = blockIdx.x, b = blockIdx.y;
    const int e = threadIdx.x * 4;
    const float* qb = qp + (b * Sc + chunk * SC) * Ec + e;
    const float* kb = kp + (b * Sc + chunk * SC) * Ec + e;

    f4 s  = (f4)(0.f);
    f4 mx = (f4)(-1e30f);
#pragma unroll 4
    for (int r = 0; r < SC; ++r) {
        f4 qf = feat4(*(const f4*)(qb + r * Ec));
        f4 kf = feat4(__builtin_nontemporal_load((const f4*)(kb + r * Ec)));
        s.x = fmaf(qf.x, kf.x, s.x);  mx.x = fmaxf(mx.x, qf.x);
        s.y = fmaf(qf.y, kf.y, s.y);  mx.y = fmaxf(mx.y, qf.y);
        s.z = fmaf(qf.z, kf.z, s.z);  mx.z = fmaxf(mx.z, qf.z);
        s.w = fmaf(qf.w, kf.w, s.w);  mx.w = fmaxf(mx.w, qf.w);
    }
    const int o = chunk * BEc + b * Ec + e;
    *(f4*)(psum + o) = s;
    *(f4*)(pmax + o) = mx;
}

// K2a: reduce NS stats chunks -> NP parts. grid = (NP, BEc/256).
__global__ void __launch_bounds__(256)
sa_red2(const float* __restrict__ psum, const float* __restrict__ pmax,
        float* __restrict__ psumB, float* __restrict__ pmaxB, int SC2) {
    const int id = blockIdx.y * 256 + threadIdx.x;
    const int p  = blockIdx.x;
    float s = 0.f, mx = -1e30f;
    int off = p * SC2 * BEc + id;
    for (int ch = 0; ch < SC2; ++ch, off += BEc) {
        s += psum[off];
        mx = fmaxf(mx, pmax[off]);
    }
    psumB[p * BEc + id] = s;
    pmaxB[p * BEc + id] = mx;
}

// K2b: finalize stats -> c[b,e] = colsum/32 (>0); eMax = c*max
__global__ void __launch_bounds__(256)
sa_stats_fin(const float* __restrict__ psumB, const float* __restrict__ pmaxB,
             float* __restrict__ cbuf, float* __restrict__ embuf) {
    const int id = blockIdx.x * blockDim.x + threadIdx.x;
    float s = 0.f, mx = -1e30f;
#pragma unroll
    for (int p = 0; p < NP; ++p) {
        s += psumB[p * BEc + id];
        mx = fmaxf(mx, pmaxB[p * BEc + id]);
    }
    const float c = s * (1.0f / 32.0f);   // 1/sqrt(1024), c > 0 guaranteed
    cbuf[id]  = c;
    embuf[id] = c * mx;
}

// ---------------- K3: partial denominator sum_s exp(c*qf - eMax) ------------
template<int SC>
__global__ void __launch_bounds__(256)
sa_den_part(const float* __restrict__ qp, const float* __restrict__ cbuf,
            const float* __restrict__ embuf, float* __restrict__ pden) {
    const int chunk = blockIdx.x, b = blockIdx.y;
    const int e = threadIdx.x * 4;
    const f4 c4 = *(const f4*)(cbuf + b * Ec + e);
    const f4 m4 = *(const f4*)(embuf + b * Ec + e);
    const float* qb = qp + (b * Sc + chunk * SC) * Ec + e;

    f4 d = (f4)(0.f);
#pragma unroll 4
    for (int r = 0; r < SC; ++r) {
        f4 qf = feat4(*(const f4*)(qb + r * Ec));
        d.x += __expf(fmaf(c4.x, qf.x, -m4.x));
        d.y += __expf(fmaf(c4.y, qf.y, -m4.y));
        d.z += __expf(fmaf(c4.z, qf.z, -m4.z));
        d.w += __expf(fmaf(c4.w, qf.w, -m4.w));
    }
    const int o = chunk * BEc + b * Ec + e;
    *(f4*)(pden + o) = d;
}

// K4a: reduce NS denom chunks -> NP parts. grid = (NP, BEc/256).
__global__ void __launch_bounds__(256)
sa_red1(const float* __restrict__ pden, float* __restrict__ pdenB, int SC2) {
    const int id = blockIdx.y * 256 + threadIdx.x;
    const int p  = blockIdx.x;
    float s = 0.f;
    int off = p * SC2 * BEc + id;
    for (int ch = 0; ch < SC2; ++ch, off += BEc) s += pden[off];
    pdenB[p * BEc + id] = s;
}

// K4b: finalize denominator -> reciprocal
__global__ void __launch_bounds__(256)
sa_den_fin(const float* __restrict__ pdenB, float* __restrict__ rdbuf) {
    const int id = blockIdx.x * blockDim.x + threadIdx.x;
    float s = 0.f;
#pragma unroll
    for (int p = 0; p < NP; ++p) s += pdenB[p * BEc + id];
    rdbuf[id] = 1.0f / s;
}

// ---------------- K5: out = exp(c*qf - eMax) * rdenom * values --------------
// V load + out store stay nontemporal: protects Q's L3 residency.
template<int SC>
__global__ void __launch_bounds__(256)
sa_out(const float* __restrict__ qp, const float* __restrict__ vp,
       const float* __restrict__ cbuf, const float* __restrict__ embuf,
       const float* __restrict__ rdbuf, float* __restrict__ outp) {
    const int chunk = blockIdx.x, b = blockIdx.y;
    const int e = threadIdx.x * 4;
    const f4 c4 = *(const f4*)(cbuf + b * Ec + e);
    const f4 m4 = *(const f4*)(embuf + b * Ec + e);
    const f4 r4 = *(const f4*)(rdbuf + b * Ec + e);
    const int base0 = (b * Sc + chunk * SC) * Ec + e;
    const float* qb = qp + base0;
    const float* vb = vp + base0;
    float* ob = outp + base0;

#pragma unroll 4
    for (int r = 0; r < SC; ++r) {
        f4 qf = feat4(*(const f4*)(qb + r * Ec));
        f4 vv = __builtin_nontemporal_load((const f4*)(vb + r * Ec));
        f4 o;
        o.x = __expf(fmaf(c4.x, qf.x, -m4.x)) * r4.x * vv.x;
        o.y = __expf(fmaf(c4.y, qf.y, -m4.y)) * r4.y * vv.y;
        o.z = __expf(fmaf(c4.z, qf.z, -m4.z)) * r4.z * vv.z;
        o.w = __expf(fmaf(c4.w, qf.w, -m4.w)) * r4.w * vv.w;
        __builtin_nontemporal_store(o, (f4*)(ob + r * Ec));
    }
}

extern "C" void kernel_launch(void* const* d_in, const int* in_sizes, int n_in,
                              void* d_out, int out_size, void* d_ws, size_t ws_size,
                              hipStream_t stream) {
    const float* q = (const float*)d_in[0];
    const float* k = (const float*)d_in[1];
    const float* v = (const float*)d_in[2];
    float* out = (float*)d_out;

    const int NS = NSmain;     // ws usage ~17 MB
    const int SC2 = NS / NP;

    float* w     = (float*)d_ws;
    float* psum  = w;
    float* pmax  = psum  + (size_t)NS * BEc;
    float* psumB = pmax  + (size_t)NS * BEc;
    float* pmaxB = psumB + (size_t)NP * BEc;
    float* cbuf  = pmaxB + (size_t)NP * BEc;
    float* embuf = cbuf  + BEc;
    float* rdbuf = embuf + BEc;
    float* pden  = psum;    // reused after K2a
    float* pdenB = psumB;   // reused after K2b

    dim3 gridP(NS, Bc);
    dim3 gridR(NP, BEc / 256);
    sa_stats_part<SCmain><<<gridP, 256, 0, stream>>>(q, k, psum, pmax);
    sa_red2<<<gridR, 256, 0, stream>>>(psum, pmax, psumB, pmaxB, SC2);
    sa_stats_fin<<<BEc / 256, 256, 0, stream>>>(psumB, pmaxB, cbuf, embuf);
    sa_den_part<SCmain><<<gridP, 256, 0, stream>>>(q, cbuf, embuf, pden);
    sa_red1<<<gridR, 256, 0, stream>>>(pden, pdenB, SC2);
    sa_den_fin<<<BEc / 256, 256, 0, stream>>>(pdenB, rdbuf);
    sa_out<SCmain><<<gridP, 256, 0, stream>>>(q, v, cbuf, embuf, rdbuf, out);
}